// Round 2
// baseline (403.875 us; speedup 1.0000x reference)
//
#include <hip/hip_runtime.h>
#include <hip/hip_bf16.h>

typedef short v8s __attribute__((ext_vector_type(8)));
typedef float f32x4 __attribute__((ext_vector_type(4)));

constexpr int Bb = 4, S = 2048, H = 16, Dd = 128;
constexpr int BQ = 64, BK = 32;
constexpr float NEG = -1e30f;

static __device__ inline short f2bs(float x) {
    __hip_bfloat16 h = __float2bfloat16(x);
    return *reinterpret_cast<short*>(&h);
}
static __device__ inline float bs2f(short s) {
    unsigned u = ((unsigned)(unsigned short)s) << 16;
    return __uint_as_float(u);
}

__global__ __launch_bounds__(256) void fa_fwd(const float* __restrict__ q,
                                              const float* __restrict__ k,
                                              const float* __restrict__ v,
                                              const int* __restrict__ seg,
                                              float* __restrict__ out) {
    // K tile as bf16 hi/lo pair [k][d] pitch 136 (rows 16B aligned),
    // V^T bf16 [d][k] pitch 40, P per-wave [q][k] pitch 40.
    __shared__ __align__(16) short Kh[BK][136];
    __shared__ __align__(16) short Kl[BK][136];
    __shared__ __align__(16) short Vt[Dd][40];
    __shared__ __align__(16) short Pl[4][16][40];

    const int qt = blockIdx.x, h = blockIdx.y, b = blockIdx.z;
    const int q0 = qt * BQ;
    const int tid = threadIdx.x;
    const int wave = tid >> 6, lane = tid & 63;
    const int quad = lane >> 4, l16 = lane & 15;

    // ---- Q fragments, hi/lo bf16 split (A-layout: m = lane&15, k = quad*8+j)
    const int rowA = q0 + wave * 16 + l16;
    const float* qbase = q + (((size_t)b * S + rowA) * H + h) * Dd;
    v8s qh[4], qlo[4];
#pragma unroll
    for (int c = 0; c < 4; ++c) {
        f32x4 x0 = *(const f32x4*)(qbase + c * 32 + quad * 8);
        f32x4 x1 = *(const f32x4*)(qbase + c * 32 + quad * 8 + 4);
#pragma unroll
        for (int i = 0; i < 4; ++i) {
            short h0 = f2bs(x0[i]); qh[c][i]     = h0; qlo[c][i]     = f2bs(x0[i] - bs2f(h0));
            short h1 = f2bs(x1[i]); qh[c][4 + i] = h1; qlo[c][4 + i] = f2bs(x1[i] - bs2f(h1));
        }
    }

    // ---- per-lane segment ids for its 4 C-layout rows
    const int rowC0 = q0 + wave * 16 + quad * 4;
    int segq[4];
#pragma unroll
    for (int r = 0; r < 4; ++r) segq[r] = seg[b * S + rowC0 + r];
    const int seg_lo = seg[b * S + q0];  // min segment in this q-block (sorted)

    f32x4 o[8];
#pragma unroll
    for (int dt = 0; dt < 8; ++dt) o[dt] = f32x4{0.f, 0.f, 0.f, 0.f};
    float m_i[4], l_i[4];
#pragma unroll
    for (int r = 0; r < 4; ++r) { m_i[r] = NEG; l_i[r] = 0.f; }

    const int nkt = (q0 + BQ) / BK;
    for (int it = 0; it < nkt; ++it) {
        const int kt = it * BK;
        // Block-uniform segment skip (seg sorted): whole tile below every query's seg.
        if (seg[b * S + kt + BK - 1] < seg_lo) continue;

        // ---- stage K (hi/lo bf16) and V^T (bf16) tiles from fp32 global
        {
            const int kk = tid >> 3, d0 = (tid & 7) * 16;
            const float* kb = k + (((size_t)b * S + kt + kk) * H + h) * Dd + d0;
            const float* vb = v + (((size_t)b * S + kt + kk) * H + h) * Dd + d0;
#pragma unroll
            for (int j = 0; j < 4; ++j) {
                f32x4 x = *(const f32x4*)(kb + j * 4);
#pragma unroll
                for (int i = 0; i < 4; ++i) {
                    short hb = f2bs(x[i]);
                    Kh[kk][d0 + j * 4 + i] = hb;
                    Kl[kk][d0 + j * 4 + i] = f2bs(x[i] - bs2f(hb));
                }
                f32x4 y = *(const f32x4*)(vb + j * 4);
#pragma unroll
                for (int i = 0; i < 4; ++i) Vt[d0 + j * 4 + i][kk] = f2bs(y[i]);
            }
        }
        __syncthreads();

        // ---- S = Q K^T, hi/lo split: qh*kh + ql*kh + qh*kl
        float sc[2][4];
#pragma unroll
        for (int nt = 0; nt < 2; ++nt) {
            f32x4 s = f32x4{0.f, 0.f, 0.f, 0.f};
#pragma unroll
            for (int c = 0; c < 4; ++c) {
                v8s kfh = *(const v8s*)&Kh[nt * 16 + l16][c * 32 + quad * 8];
                v8s kfl = *(const v8s*)&Kl[nt * 16 + l16][c * 32 + quad * 8];
                s = __builtin_amdgcn_mfma_f32_16x16x32_bf16(qh[c], kfh, s, 0, 0, 0);
                s = __builtin_amdgcn_mfma_f32_16x16x32_bf16(qlo[c], kfh, s, 0, 0, 0);
                s = __builtin_amdgcn_mfma_f32_16x16x32_bf16(qh[c], kfl, s, 0, 0, 0);
            }
            const int kj = kt + nt * 16 + l16;
            const int segk = seg[b * S + kj];
#pragma unroll
            for (int r = 0; r < 4; ++r) {
                const int qi = rowC0 + r;
                const bool valid = (kj <= qi) && (segk == segq[r]);
                sc[nt][r] = valid ? s[r] : NEG;
            }
        }

        // ---- online softmax (each C-row lives in one 16-lane group)
        float pr[2][4];
#pragma unroll
        for (int r = 0; r < 4; ++r) {
            float mx = fmaxf(sc[0][r], sc[1][r]);
#pragma unroll
            for (int off = 1; off < 16; off <<= 1) mx = fmaxf(mx, __shfl_xor(mx, off));
            const float mn = fmaxf(m_i[r], mx);
            const float alpha = __expf(m_i[r] - mn);
            const float p0 = (sc[0][r] <= 0.5f * NEG) ? 0.f : __expf(sc[0][r] - mn);
            const float p1 = (sc[1][r] <= 0.5f * NEG) ? 0.f : __expf(sc[1][r] - mn);
            float rs = p0 + p1;
#pragma unroll
            for (int off = 1; off < 16; off <<= 1) rs += __shfl_xor(rs, off);
            l_i[r] = l_i[r] * alpha + rs;
            m_i[r] = mn;
#pragma unroll
            for (int dt = 0; dt < 8; ++dt) o[dt][r] *= alpha;
            pr[0][r] = p0;
            pr[1][r] = p1;
        }

        // ---- P: C-layout -> LDS -> A-layout (bf16)
#pragma unroll
        for (int nt = 0; nt < 2; ++nt)
#pragma unroll
            for (int r = 0; r < 4; ++r)
                Pl[wave][quad * 4 + r][nt * 16 + l16] = f2bs(pr[nt][r]);
        __syncthreads();

        // ---- O += P V
        v8s pf = *(const v8s*)&Pl[wave][l16][quad * 8];
#pragma unroll
        for (int dt = 0; dt < 8; ++dt) {
            v8s vf = *(const v8s*)&Vt[dt * 16 + l16][quad * 8];
            o[dt] = __builtin_amdgcn_mfma_f32_16x16x32_bf16(pf, vf, o[dt], 0, 0, 0);
        }
        __syncthreads();  // before next iteration overwrites tiles
    }

    // ---- epilogue: divide by l_i, store fp32
    const size_t obase = (((size_t)b * S + rowC0) * H + h) * Dd;
#pragma unroll
    for (int r = 0; r < 4; ++r) {
        const float inv = 1.0f / l_i[r];  // every row has its causal self-key
#pragma unroll
        for (int dt = 0; dt < 8; ++dt)
            out[obase + (size_t)r * H * Dd + dt * 16 + l16] = o[dt][r] * inv;
    }
}

extern "C" void kernel_launch(void* const* d_in, const int* in_sizes, int n_in,
                              void* d_out, int out_size, void* d_ws, size_t ws_size,
                              hipStream_t stream) {
    const float* q = (const float*)d_in[0];
    const float* k = (const float*)d_in[1];
    const float* v = (const float*)d_in[2];
    const int* seg = (const int*)d_in[3];
    float* out = (float*)d_out;
    dim3 grid(S / BQ, H, Bb);
    fa_fwd<<<grid, dim3(256), 0, stream>>>(q, k, v, seg, out);
}

// Round 3
// 395.033 us; speedup vs baseline: 1.0224x; 1.0224x over previous
//
#include <hip/hip_runtime.h>
#include <hip/hip_bf16.h>

typedef short v8s __attribute__((ext_vector_type(8)));
typedef float f32x4 __attribute__((ext_vector_type(4)));

constexpr int Bb = 4, S = 2048, H = 16, Dd = 128;
constexpr int BQ = 64, BK = 32;
constexpr float NEG = -1e30f;
constexpr size_t NELEM = (size_t)Bb * S * H * Dd;  // 16.7M

static __device__ inline short f2bs(float x) {
    __hip_bfloat16 h = __float2bfloat16(x);
    return *reinterpret_cast<short*>(&h);
}
static __device__ inline float bs2f(short s) {
    unsigned u = ((unsigned)(unsigned short)s) << 16;
    return __uint_as_float(u);
}

// ============ prepass 1: K (fp32) -> Khi,Klo (bf16), same [b,s,h,d] layout
__global__ __launch_bounds__(256) void prep_k(const float* __restrict__ k,
                                              short* __restrict__ khi,
                                              short* __restrict__ klo) {
    size_t i = ((size_t)blockIdx.x * 256 + threadIdx.x) * 8;
    f32x4 a = *(const f32x4*)(k + i);
    f32x4 b = *(const f32x4*)(k + i + 4);
    v8s hi, lo;
#pragma unroll
    for (int j = 0; j < 4; ++j) {
        short h0 = f2bs(a[j]); hi[j] = h0;     lo[j] = f2bs(a[j] - bs2f(h0));
        short h1 = f2bs(b[j]); hi[4 + j] = h1; lo[4 + j] = f2bs(b[j] - bs2f(h1));
    }
    *(v8s*)(khi + i) = hi;
    *(v8s*)(klo + i) = lo;
}

// ============ prepass 2: V (fp32 [b,s,h,d]) -> Vt (bf16 [b,h,d,s])
__global__ __launch_bounds__(256) void prep_vt(const float* __restrict__ v,
                                               short* __restrict__ vt) {
    __shared__ __align__(16) short T[64][136];  // pitch 136: 16B-aligned rows, conflict-free
    const int k0 = blockIdx.x * 64, h = blockIdx.y, b = blockIdx.z;
    const int t = threadIdx.x;
    {   // load+convert 64 k-rows x 128 d
        const int kk = t >> 2, c0 = (t & 3) * 32;
        const float* vb = v + (((size_t)b * S + k0 + kk) * H + h) * Dd + c0;
        short tmp[32];
#pragma unroll
        for (int j = 0; j < 32; j += 4) {
            f32x4 x = *(const f32x4*)(vb + j);
#pragma unroll
            for (int i = 0; i < 4; ++i) tmp[j + i] = f2bs(x[i]);
        }
#pragma unroll
        for (int j = 0; j < 4; ++j) *(v8s*)&T[kk][c0 + j * 8] = *(v8s*)&tmp[j * 8];
    }
    __syncthreads();
    {   // write transposed: row d, 64 k contiguous
        const int d = t >> 1, koff = (t & 1) * 32;
        short o16[32];
#pragma unroll
        for (int i = 0; i < 32; ++i) o16[i] = T[koff + i][d];
        short* dst = vt + ((size_t)(b * H + h) * Dd + d) * S + k0 + koff;
#pragma unroll
        for (int j = 0; j < 4; ++j) *(v8s*)(dst + j * 8) = *(v8s*)&o16[j * 8];
    }
}

// ============ main flash kernel (pre-converted K/V)
__global__ __launch_bounds__(256) void fa_fast(const short* __restrict__ khi,
                                               const short* __restrict__ klo,
                                               const short* __restrict__ vtg,
                                               const float* __restrict__ q,
                                               const int* __restrict__ seg,
                                               float* __restrict__ out) {
    __shared__ __align__(16) short Khl[BK][136];
    __shared__ __align__(16) short Kll[BK][136];
    __shared__ __align__(16) short Vtl[Dd][40];
    __shared__ __align__(16) short Pl[4][16][40];

    const int qt = blockIdx.x, h = blockIdx.y, b = blockIdx.z;
    const int q0 = qt * BQ, tid = threadIdx.x;
    const int wave = tid >> 6, lane = tid & 63;
    const int quad = lane >> 4, l16 = lane & 15;

    // Q fragments hi/lo (A-layout: m=lane&15, k=quad*8+j); converted once per block
    const int rowA = q0 + wave * 16 + l16;
    const float* qbase = q + (((size_t)b * S + rowA) * H + h) * Dd;
    v8s qh[4], ql[4];
#pragma unroll
    for (int c = 0; c < 4; ++c) {
        f32x4 x0 = *(const f32x4*)(qbase + c * 32 + quad * 8);
        f32x4 x1 = *(const f32x4*)(qbase + c * 32 + quad * 8 + 4);
#pragma unroll
        for (int i = 0; i < 4; ++i) {
            short h0 = f2bs(x0[i]); qh[c][i] = h0;     ql[c][i] = f2bs(x0[i] - bs2f(h0));
            short h1 = f2bs(x1[i]); qh[c][4 + i] = h1; ql[c][4 + i] = f2bs(x1[i] - bs2f(h1));
        }
    }

    const int rowC0 = q0 + wave * 16 + quad * 4;
    const int segb = b * S;
    int segq[4];
#pragma unroll
    for (int r = 0; r < 4; ++r) segq[r] = seg[segb + rowC0 + r];
    const int seg_lo = seg[segb + q0];

    f32x4 o[8];
#pragma unroll
    for (int dt = 0; dt < 8; ++dt) o[dt] = f32x4{0.f, 0.f, 0.f, 0.f};
    float m_i[4], l_i[4];
#pragma unroll
    for (int r = 0; r < 4; ++r) { m_i[r] = NEG; l_i[r] = 0.f; }

    // staging assignment: pure 16B copies, conflict-free LDS layout
    const int skk = tid >> 3, scol = (tid & 7) * 16;   // K: row 0..31, 16 shorts
    const int svd = tid >> 1, svo = (tid & 1) * 16;    // Vt: row 0..127, 16 shorts
    const size_t kbase = (((size_t)b * S + skk) * H + h) * Dd + scol;  // + kt*H*Dd
    const size_t vbase = ((size_t)(b * H + h) * Dd + svd) * S + svo;   // + kt

    const int nkt = (q0 + BQ) / BK;
    int it = 0;
    while (it < nkt && seg[segb + it * BK + BK - 1] < seg_lo) ++it;

    v8s pA, pB, pC, pD, pE, pF;
    if (it < nkt) {
        const size_t ka = kbase + (size_t)it * BK * H * Dd;
        pA = *(const v8s*)(khi + ka); pB = *(const v8s*)(khi + ka + 8);
        pC = *(const v8s*)(klo + ka); pD = *(const v8s*)(klo + ka + 8);
        const size_t va = vbase + (size_t)it * BK;
        pE = *(const v8s*)(vtg + va); pF = *(const v8s*)(vtg + va + 8);
    }

    while (it < nkt) {
        // commit prefetched tile to LDS
        *(v8s*)&Khl[skk][scol] = pA; *(v8s*)&Khl[skk][scol + 8] = pB;
        *(v8s*)&Kll[skk][scol] = pC; *(v8s*)&Kll[skk][scol + 8] = pD;
        *(v8s*)&Vtl[svd][svo]  = pE; *(v8s*)&Vtl[svd][svo + 8]  = pF;
        __syncthreads();

        const int kt = it * BK;
        int nit = it + 1;
        while (nit < nkt && seg[segb + nit * BK + BK - 1] < seg_lo) ++nit;
        if (nit < nkt) {  // prefetch next tile; vmcnt drains at next iteration's stores
            const size_t ka = kbase + (size_t)nit * BK * H * Dd;
            pA = *(const v8s*)(khi + ka); pB = *(const v8s*)(khi + ka + 8);
            pC = *(const v8s*)(klo + ka); pD = *(const v8s*)(klo + ka + 8);
            const size_t va = vbase + (size_t)nit * BK;
            pE = *(const v8s*)(vtg + va); pF = *(const v8s*)(vtg + va + 8);
        }

        // ---- S = Q K^T (hi/lo split: qh*kh + ql*kh + qh*kl)
        float sc_[2][4];
#pragma unroll
        for (int nt = 0; nt < 2; ++nt) {
            f32x4 s = f32x4{0.f, 0.f, 0.f, 0.f};
#pragma unroll
            for (int c = 0; c < 4; ++c) {
                v8s kfh = *(const v8s*)&Khl[nt * 16 + l16][c * 32 + quad * 8];
                v8s kfl = *(const v8s*)&Kll[nt * 16 + l16][c * 32 + quad * 8];
                s = __builtin_amdgcn_mfma_f32_16x16x32_bf16(qh[c], kfh, s, 0, 0, 0);
                s = __builtin_amdgcn_mfma_f32_16x16x32_bf16(ql[c], kfh, s, 0, 0, 0);
                s = __builtin_amdgcn_mfma_f32_16x16x32_bf16(qh[c], kfl, s, 0, 0, 0);
            }
            const int kj = kt + nt * 16 + l16;
            const int sk = seg[segb + kj];
#pragma unroll
            for (int r = 0; r < 4; ++r) {
                const bool valid = (kj <= rowC0 + r) && (sk == segq[r]);
                sc_[nt][r] = valid ? s[r] : NEG;
            }
        }

        // ---- online softmax
        float pr[2][4];
#pragma unroll
        for (int r = 0; r < 4; ++r) {
            float mx = fmaxf(sc_[0][r], sc_[1][r]);
#pragma unroll
            for (int off = 1; off < 16; off <<= 1) mx = fmaxf(mx, __shfl_xor(mx, off));
            const float mn = fmaxf(m_i[r], mx);
            const float alpha = __expf(m_i[r] - mn);
            const float p0 = (sc_[0][r] <= 0.5f * NEG) ? 0.f : __expf(sc_[0][r] - mn);
            const float p1 = (sc_[1][r] <= 0.5f * NEG) ? 0.f : __expf(sc_[1][r] - mn);
            float rs = p0 + p1;
#pragma unroll
            for (int off = 1; off < 16; off <<= 1) rs += __shfl_xor(rs, off);
            l_i[r] = l_i[r] * alpha + rs;
            m_i[r] = mn;
#pragma unroll
            for (int dt = 0; dt < 8; ++dt) o[dt][r] *= alpha;
            pr[0][r] = p0;
            pr[1][r] = p1;
        }

        // ---- P: C-layout -> LDS -> A-layout. Pl is wave-private: NO barrier
        // needed (intra-wave LDS ordering via lgkmcnt).
#pragma unroll
        for (int nt = 0; nt < 2; ++nt)
#pragma unroll
            for (int r = 0; r < 4; ++r)
                Pl[wave][quad * 4 + r][nt * 16 + l16] = f2bs(pr[nt][r]);

        v8s pf = *(const v8s*)&Pl[wave][l16][quad * 8];
#pragma unroll
        for (int dt = 0; dt < 8; ++dt) {
            v8s vf = *(const v8s*)&Vtl[dt * 16 + l16][quad * 8];
            o[dt] = __builtin_amdgcn_mfma_f32_16x16x32_bf16(pf, vf, o[dt], 0, 0, 0);
        }
        __syncthreads();  // Khl/Kll/Vtl reads done before next store
        it = nit;
    }

    const size_t obase = (((size_t)b * S + rowC0) * H + h) * Dd;
#pragma unroll
    for (int r = 0; r < 4; ++r) {
        const float inv = 1.0f / l_i[r];
#pragma unroll
        for (int dt = 0; dt < 8; ++dt)
            out[obase + (size_t)r * H * Dd + dt * 16 + l16] = o[dt][r] * inv;
    }
}

// ============ fallback (R2 kernel): used only if ws_size is too small
__global__ __launch_bounds__(256) void fa_slow(const float* __restrict__ q,
                                               const float* __restrict__ k,
                                               const float* __restrict__ v,
                                               const int* __restrict__ seg,
                                               float* __restrict__ out) {
    __shared__ __align__(16) short Kh[BK][136];
    __shared__ __align__(16) short Kl[BK][136];
    __shared__ __align__(16) short Vt[Dd][40];
    __shared__ __align__(16) short Pl[4][16][40];
    const int qt = blockIdx.x, h = blockIdx.y, b = blockIdx.z;
    const int q0 = qt * BQ, tid = threadIdx.x;
    const int wave = tid >> 6, lane = tid & 63;
    const int quad = lane >> 4, l16 = lane & 15;
    const int rowA = q0 + wave * 16 + l16;
    const float* qbase = q + (((size_t)b * S + rowA) * H + h) * Dd;
    v8s qh[4], qlo[4];
#pragma unroll
    for (int c = 0; c < 4; ++c) {
        f32x4 x0 = *(const f32x4*)(qbase + c * 32 + quad * 8);
        f32x4 x1 = *(const f32x4*)(qbase + c * 32 + quad * 8 + 4);
#pragma unroll
        for (int i = 0; i < 4; ++i) {
            short h0 = f2bs(x0[i]); qh[c][i] = h0;     qlo[c][i] = f2bs(x0[i] - bs2f(h0));
            short h1 = f2bs(x1[i]); qh[c][4 + i] = h1; qlo[c][4 + i] = f2bs(x1[i] - bs2f(h1));
        }
    }
    const int rowC0 = q0 + wave * 16 + quad * 4;
    int segq[4];
#pragma unroll
    for (int r = 0; r < 4; ++r) segq[r] = seg[b * S + rowC0 + r];
    const int seg_lo = seg[b * S + q0];
    f32x4 o[8];
#pragma unroll
    for (int dt = 0; dt < 8; ++dt) o[dt] = f32x4{0.f, 0.f, 0.f, 0.f};
    float m_i[4], l_i[4];
#pragma unroll
    for (int r = 0; r < 4; ++r) { m_i[r] = NEG; l_i[r] = 0.f; }
    const int nkt = (q0 + BQ) / BK;
    for (int itx = 0; itx < nkt; ++itx) {
        const int kt = itx * BK;
        if (seg[b * S + kt + BK - 1] < seg_lo) continue;
        {
            const int kk = tid >> 3, d0 = (tid & 7) * 16;
            const float* kb = k + (((size_t)b * S + kt + kk) * H + h) * Dd + d0;
            const float* vb = v + (((size_t)b * S + kt + kk) * H + h) * Dd + d0;
#pragma unroll
            for (int j = 0; j < 4; ++j) {
                f32x4 x = *(const f32x4*)(kb + j * 4);
#pragma unroll
                for (int i = 0; i < 4; ++i) {
                    short hb = f2bs(x[i]);
                    Kh[kk][d0 + j * 4 + i] = hb;
                    Kl[kk][d0 + j * 4 + i] = f2bs(x[i] - bs2f(hb));
                }
                f32x4 y = *(const f32x4*)(vb + j * 4);
#pragma unroll
                for (int i = 0; i < 4; ++i) Vt[d0 + j * 4 + i][kk] = f2bs(y[i]);
            }
        }
        __syncthreads();
        float sc_[2][4];
#pragma unroll
        for (int nt = 0; nt < 2; ++nt) {
            f32x4 s = f32x4{0.f, 0.f, 0.f, 0.f};
#pragma unroll
            for (int c = 0; c < 4; ++c) {
                v8s kfh = *(const v8s*)&Kh[nt * 16 + l16][c * 32 + quad * 8];
                v8s kfl = *(const v8s*)&Kl[nt * 16 + l16][c * 32 + quad * 8];
                s = __builtin_amdgcn_mfma_f32_16x16x32_bf16(qh[c], kfh, s, 0, 0, 0);
                s = __builtin_amdgcn_mfma_f32_16x16x32_bf16(qlo[c], kfh, s, 0, 0, 0);
                s = __builtin_amdgcn_mfma_f32_16x16x32_bf16(qh[c], kfl, s, 0, 0, 0);
            }
            const int kj = kt + nt * 16 + l16;
            const int segk = seg[b * S + kj];
#pragma unroll
            for (int r = 0; r < 4; ++r) {
                const bool valid = (kj <= rowC0 + r) && (segk == segq[r]);
                sc_[nt][r] = valid ? s[r] : NEG;
            }
        }
        float pr[2][4];
#pragma unroll
        for (int r = 0; r < 4; ++r) {
            float mx = fmaxf(sc_[0][r], sc_[1][r]);
#pragma unroll
            for (int off = 1; off < 16; off <<= 1) mx = fmaxf(mx, __shfl_xor(mx, off));
            const float mn = fmaxf(m_i[r], mx);
            const float alpha = __expf(m_i[r] - mn);
            const float p0 = (sc_[0][r] <= 0.5f * NEG) ? 0.f : __expf(sc_[0][r] - mn);
            const float p1 = (sc_[1][r] <= 0.5f * NEG) ? 0.f : __expf(sc_[1][r] - mn);
            float rs = p0 + p1;
#pragma unroll
            for (int off = 1; off < 16; off <<= 1) rs += __shfl_xor(rs, off);
            l_i[r] = l_i[r] * alpha + rs;
            m_i[r] = mn;
#pragma unroll
            for (int dt = 0; dt < 8; ++dt) o[dt][r] *= alpha;
            pr[0][r] = p0;
            pr[1][r] = p1;
        }
#pragma unroll
        for (int nt = 0; nt < 2; ++nt)
#pragma unroll
            for (int r = 0; r < 4; ++r)
                Pl[wave][quad * 4 + r][nt * 16 + l16] = f2bs(pr[nt][r]);
        v8s pf = *(const v8s*)&Pl[wave][l16][quad * 8];
#pragma unroll
        for (int dt = 0; dt < 8; ++dt) {
            v8s vf = *(const v8s*)&Vt[dt * 16 + l16][quad * 8];
            o[dt] = __builtin_amdgcn_mfma_f32_16x16x32_bf16(pf, vf, o[dt], 0, 0, 0);
        }
        __syncthreads();
    }
    const size_t obase = (((size_t)b * S + rowC0) * H + h) * Dd;
#pragma unroll
    for (int r = 0; r < 4; ++r) {
        const float inv = 1.0f / l_i[r];
#pragma unroll
        for (int dt = 0; dt < 8; ++dt)
            out[obase + (size_t)r * H * Dd + dt * 16 + l16] = o[dt][r] * inv;
    }
}

extern "C" void kernel_launch(void* const* d_in, const int* in_sizes, int n_in,
                              void* d_out, int out_size, void* d_ws, size_t ws_size,
                              hipStream_t stream) {
    const float* q = (const float*)d_in[0];
    const float* k = (const float*)d_in[1];
    const float* v = (const float*)d_in[2];
    const int* seg = (const int*)d_in[3];
    float* out = (float*)d_out;
    const size_t need = NELEM * 2 * 3;  // Khi + Klo + Vt, bf16
    dim3 grid(S / BQ, H, Bb);
    if (ws_size >= need) {
        short* khi = (short*)d_ws;
        short* klo = khi + NELEM;
        short* vtg = klo + NELEM;
        prep_k<<<(int)(NELEM / (256 * 8)), 256, 0, stream>>>(k, khi, klo);
        prep_vt<<<dim3(S / 64, H, Bb), 256, 0, stream>>>(v, vtg);
        fa_fast<<<grid, dim3(256), 0, stream>>>(khi, klo, vtg, q, seg, out);
    } else {
        fa_slow<<<grid, dim3(256), 0, stream>>>(q, k, v, seg, out);
    }
}

// Round 4
// 334.213 us; speedup vs baseline: 1.2084x; 1.1820x over previous
//
#include <hip/hip_runtime.h>
#include <hip/hip_bf16.h>

typedef short v8s __attribute__((ext_vector_type(8)));
typedef short v4s __attribute__((ext_vector_type(4)));
typedef int   v4i __attribute__((ext_vector_type(4)));
typedef float f32x4 __attribute__((ext_vector_type(4)));

constexpr int Bb = 4, S = 2048, H = 16, Dd = 128;
constexpr int BQ = 128, BK = 32;
constexpr float NEG = -1e30f;
constexpr size_t NELEM = (size_t)Bb * S * H * Dd;  // 16.7M

static __device__ inline short f2bs(float x) {
    __hip_bfloat16 h = __float2bfloat16(x);
    return *reinterpret_cast<short*>(&h);
}
static __device__ inline float bs2f(short s) {
    unsigned u = ((unsigned)(unsigned short)s) << 16;
    return __uint_as_float(u);
}

// ============ merged prepass: K -> Khi/Klo (bf16, [b,s,h,d]); V -> Vt (bf16, [b,h,d,s])
__global__ __launch_bounds__(256) void prep(const float* __restrict__ k,
                                            const float* __restrict__ v,
                                            short* __restrict__ khi,
                                            short* __restrict__ klo,
                                            short* __restrict__ vt) {
    __shared__ __align__(16) short T[64][136];
    const int k0 = blockIdx.x * 64, h = blockIdx.y, b = blockIdx.z;
    const int t = threadIdx.x;
    const int kk = t >> 2, c0 = (t & 3) * 32;
    const size_t off = (((size_t)b * S + k0 + kk) * H + h) * Dd + c0;
    {   // K hi/lo elementwise
        short hi[32], lo[32];
#pragma unroll
        for (int j = 0; j < 8; ++j) {
            f32x4 x = *(const f32x4*)(k + off + j * 4);
#pragma unroll
            for (int i = 0; i < 4; ++i) {
                short hb = f2bs(x[i]);
                hi[j * 4 + i] = hb;
                lo[j * 4 + i] = f2bs(x[i] - bs2f(hb));
            }
        }
#pragma unroll
        for (int j = 0; j < 4; ++j) {
            *(v8s*)(khi + off + j * 8) = *(v8s*)&hi[j * 8];
            *(v8s*)(klo + off + j * 8) = *(v8s*)&lo[j * 8];
        }
    }
    {   // V convert into LDS tile
        short tmp[32];
#pragma unroll
        for (int j = 0; j < 8; ++j) {
            f32x4 x = *(const f32x4*)(v + off + j * 4);
#pragma unroll
            for (int i = 0; i < 4; ++i) tmp[j * 4 + i] = f2bs(x[i]);
        }
#pragma unroll
        for (int j = 0; j < 4; ++j) *(v8s*)&T[kk][c0 + j * 8] = *(v8s*)&tmp[j * 8];
    }
    __syncthreads();
    {   // write transposed
        const int d = t >> 1, koff = (t & 1) * 32;
        short o16[32];
#pragma unroll
        for (int i = 0; i < 32; ++i) o16[i] = T[koff + i][d];
        short* dst = vt + ((size_t)(b * H + h) * Dd + d) * S + k0 + koff;
#pragma unroll
        for (int j = 0; j < 4; ++j) *(v8s*)(dst + j * 8) = *(v8s*)&o16[j * 8];
    }
}

// ============ main flash kernel: S^T trick, wave owns 32 q-rows
__global__ __launch_bounds__(256, 2) void fa2(const short* __restrict__ khi,
                                              const short* __restrict__ klo,
                                              const short* __restrict__ vtg,
                                              const float* __restrict__ q,
                                              const int* __restrict__ seg,
                                              float* __restrict__ out) {
    __shared__ __align__(16) short Khl[BK][136];
    __shared__ __align__(16) short Kll[BK][136];
    __shared__ __align__(16) short Vtl[Dd][40];
    __shared__ __align__(16) short Pl[4][32][40];

    const int qt = gridDim.x - 1 - blockIdx.x;  // heavy (large-qt) blocks dispatch first
    const int h = blockIdx.y, b = blockIdx.z;
    const int q0 = qt * BQ, tid = threadIdx.x;
    const int w = tid >> 6, lane = tid & 63;
    const int quad = lane >> 4, l16 = lane & 15;
    const int segb = b * S;

    // ---- Q in registers, hi/lo split. Q is the MFMA *B* operand:
    // B[n=lane&15 -> q][k=quad*8+j -> d]. Two 16-row subtiles m=0,1.
    v8s qh[2][4], ql[2][4];
    int segq[2], qg[2];
#pragma unroll
    for (int m = 0; m < 2; ++m) {
        qg[m] = q0 + w * 32 + m * 16 + l16;
        const float* qb = q + (((size_t)b * S + qg[m]) * H + h) * Dd;
#pragma unroll
        for (int c = 0; c < 4; ++c) {
            f32x4 x0 = *(const f32x4*)(qb + c * 32 + quad * 8);
            f32x4 x1 = *(const f32x4*)(qb + c * 32 + quad * 8 + 4);
#pragma unroll
            for (int i = 0; i < 4; ++i) {
                short h0 = f2bs(x0[i]); qh[m][c][i] = h0;     ql[m][c][i] = f2bs(x0[i] - bs2f(h0));
                short h1 = f2bs(x1[i]); qh[m][c][4 + i] = h1; ql[m][c][4 + i] = f2bs(x1[i] - bs2f(h1));
            }
        }
        segq[m] = seg[segb + qg[m]];
    }
    const int seg_lo = seg[segb + q0];

    f32x4 o[2][8];
#pragma unroll
    for (int m = 0; m < 2; ++m)
#pragma unroll
        for (int dt = 0; dt < 8; ++dt) o[m][dt] = f32x4{0.f, 0.f, 0.f, 0.f};
    float m_i[2] = {NEG, NEG}, l_i[2] = {0.f, 0.f};

    // staging assignment (pure 16B copies)
    const int skk = tid >> 3, scol = (tid & 7) * 16;
    const int svd = tid >> 1, svo = (tid & 1) * 16;
    const size_t kstage = (((size_t)b * S + skk) * H + h) * Dd + scol;
    const size_t vstage = ((size_t)(b * H + h) * Dd + svd) * S + svo;

    const int nkt = (q0 + BQ) / BK;
    int it = 0;
    while (it < nkt && seg[segb + it * BK + BK - 1] < seg_lo) ++it;

    v8s pA, pB, pC, pD, pE, pF;
    if (it < nkt) {
        const size_t ka = kstage + (size_t)it * BK * H * Dd;
        pA = *(const v8s*)(khi + ka); pB = *(const v8s*)(khi + ka + 8);
        pC = *(const v8s*)(klo + ka); pD = *(const v8s*)(klo + ka + 8);
        const size_t va = vstage + (size_t)it * BK;
        pE = *(const v8s*)(vtg + va); pF = *(const v8s*)(vtg + va + 8);
    }

    while (it < nkt) {
        *(v8s*)&Khl[skk][scol] = pA; *(v8s*)&Khl[skk][scol + 8] = pB;
        *(v8s*)&Kll[skk][scol] = pC; *(v8s*)&Kll[skk][scol + 8] = pD;
        *(v8s*)&Vtl[svd][svo]  = pE; *(v8s*)&Vtl[svd][svo + 8]  = pF;
        __syncthreads();

        const int kt = it * BK;
        int nit = it + 1;
        while (nit < nkt && seg[segb + nit * BK + BK - 1] < seg_lo) ++nit;
        if (nit < nkt) {
            const size_t ka = kstage + (size_t)nit * BK * H * Dd;
            pA = *(const v8s*)(khi + ka); pB = *(const v8s*)(khi + ka + 8);
            pC = *(const v8s*)(klo + ka); pD = *(const v8s*)(klo + ka + 8);
            const size_t va = vstage + (size_t)nit * BK;
            pE = *(const v8s*)(vtg + va); pF = *(const v8s*)(vtg + va + 8);
        }

        // segment ids of this tile's k rows (per lane: rows quad*4+r, +16*nt)
        v4i sk0 = *(const v4i*)(seg + segb + kt + quad * 4);
        v4i sk1 = *(const v4i*)(seg + segb + kt + 16 + quad * 4);

        // ---- S^T = K Q^T: C layout col=q (l16), row=k' (quad*4+r).
        // K-frag reads shared across both m-subtiles.
        float sc_[2][2][4];  // [m][nt][r]
#pragma unroll
        for (int nt = 0; nt < 2; ++nt) {
            v8s kfh[4], kfl[4];
#pragma unroll
            for (int c = 0; c < 4; ++c) {
                kfh[c] = *(const v8s*)&Khl[nt * 16 + l16][c * 32 + quad * 8];
                kfl[c] = *(const v8s*)&Kll[nt * 16 + l16][c * 32 + quad * 8];
            }
#pragma unroll
            for (int m = 0; m < 2; ++m) {
                f32x4 s = f32x4{0.f, 0.f, 0.f, 0.f};
#pragma unroll
                for (int c = 0; c < 4; ++c) {
                    s = __builtin_amdgcn_mfma_f32_16x16x32_bf16(kfh[c], qh[m][c], s, 0, 0, 0);
                    s = __builtin_amdgcn_mfma_f32_16x16x32_bf16(kfl[c], qh[m][c], s, 0, 0, 0);
                    s = __builtin_amdgcn_mfma_f32_16x16x32_bf16(kfh[c], ql[m][c], s, 0, 0, 0);
                }
                const v4i skv = nt ? sk1 : sk0;
#pragma unroll
                for (int r = 0; r < 4; ++r) {
                    const int kg = kt + nt * 16 + quad * 4 + r;
                    const bool valid = (kg <= qg[m]) && (skv[r] == segq[m]);
                    sc_[m][nt][r] = valid ? s[r] : NEG;
                }
            }
        }

        // ---- online softmax per m-subtile; each lane owns q-row qg[m],
        // its 32 k-values live in 4 lanes (l16 class) x 8 regs.
#pragma unroll
        for (int m = 0; m < 2; ++m) {
            float mx = sc_[m][0][0];
#pragma unroll
            for (int nt = 0; nt < 2; ++nt)
#pragma unroll
                for (int r = 0; r < 4; ++r) mx = fmaxf(mx, sc_[m][nt][r]);
            mx = fmaxf(mx, __shfl_xor(mx, 16));
            mx = fmaxf(mx, __shfl_xor(mx, 32));
            const float mn = fmaxf(m_i[m], mx);
            const float alpha = __expf(m_i[m] - mn);
            float pv[2][4], rs = 0.f;
#pragma unroll
            for (int nt = 0; nt < 2; ++nt)
#pragma unroll
                for (int r = 0; r < 4; ++r) {
                    const float p = (sc_[m][nt][r] <= 0.5f * NEG) ? 0.f : __expf(sc_[m][nt][r] - mn);
                    pv[nt][r] = p;
                    rs += p;
                }
            rs += __shfl_xor(rs, 16);
            rs += __shfl_xor(rs, 32);
            l_i[m] = l_i[m] * alpha + rs;
            m_i[m] = mn;

            // P write: row = m*16+l16 (q), cols nt*16+quad*4..+3 -> one b64 per nt
#pragma unroll
            for (int nt = 0; nt < 2; ++nt) {
                v4s pk;
#pragma unroll
                for (int r = 0; r < 4; ++r) pk[r] = f2bs(pv[nt][r]);
                *(v4s*)&Pl[w][m * 16 + l16][nt * 16 + quad * 4] = pk;
            }

            // O rescale: O rows are quad*4+r -> fetch alpha from lane with that l16
#pragma unroll
            for (int r = 0; r < 4; ++r) {
                const float ar = __shfl(alpha, (lane & 48) + quad * 4 + r);
#pragma unroll
                for (int dt = 0; dt < 8; ++dt) o[m][dt][r] *= ar;
            }
        }

        // ---- O += P V (Pl wave-private: intra-wave lgkm ordering, no barrier)
        v8s pf[2];
#pragma unroll
        for (int m = 0; m < 2; ++m) pf[m] = *(const v8s*)&Pl[w][m * 16 + l16][quad * 8];
#pragma unroll
        for (int dt = 0; dt < 8; ++dt) {
            v8s vf = *(const v8s*)&Vtl[dt * 16 + l16][quad * 8];
#pragma unroll
            for (int m = 0; m < 2; ++m)
                o[m][dt] = __builtin_amdgcn_mfma_f32_16x16x32_bf16(pf[m], vf, o[m][dt], 0, 0, 0);
        }
        __syncthreads();
        it = nit;
    }

    // ---- epilogue
#pragma unroll
    for (int m = 0; m < 2; ++m)
#pragma unroll
        for (int r = 0; r < 4; ++r) {
            const float lr = __shfl(l_i[m], (lane & 48) + quad * 4 + r);
            const float inv = 1.0f / lr;
            const int qrow = q0 + w * 32 + m * 16 + quad * 4 + r;
            const size_t ob = (((size_t)b * S + qrow) * H + h) * Dd;
#pragma unroll
            for (int dt = 0; dt < 8; ++dt)
                out[ob + dt * 16 + l16] = o[m][dt][r] * inv;
        }
}

// ============ fallback (R2-style, no workspace)
__global__ __launch_bounds__(256) void fa_slow(const float* __restrict__ q,
                                               const float* __restrict__ k,
                                               const float* __restrict__ v,
                                               const int* __restrict__ seg,
                                               float* __restrict__ out) {
    __shared__ __align__(16) short Kh[32][136];
    __shared__ __align__(16) short Kl[32][136];
    __shared__ __align__(16) short Vt[Dd][40];
    __shared__ __align__(16) short Pl[4][16][40];
    const int qt = blockIdx.x, h = blockIdx.y, b = blockIdx.z;
    const int q0 = qt * 64, tid = threadIdx.x;
    const int wave = tid >> 6, lane = tid & 63;
    const int quad = lane >> 4, l16 = lane & 15;
    const int rowA = q0 + wave * 16 + l16;
    const float* qbase = q + (((size_t)b * S + rowA) * H + h) * Dd;
    v8s qh[4], qlo[4];
#pragma unroll
    for (int c = 0; c < 4; ++c) {
        f32x4 x0 = *(const f32x4*)(qbase + c * 32 + quad * 8);
        f32x4 x1 = *(const f32x4*)(qbase + c * 32 + quad * 8 + 4);
#pragma unroll
        for (int i = 0; i < 4; ++i) {
            short h0 = f2bs(x0[i]); qh[c][i] = h0;     qlo[c][i] = f2bs(x0[i] - bs2f(h0));
            short h1 = f2bs(x1[i]); qh[c][4 + i] = h1; qlo[c][4 + i] = f2bs(x1[i] - bs2f(h1));
        }
    }
    const int rowC0 = q0 + wave * 16 + quad * 4;
    int segq[4];
#pragma unroll
    for (int r = 0; r < 4; ++r) segq[r] = seg[b * S + rowC0 + r];
    const int seg_lo = seg[b * S + q0];
    f32x4 o[8];
#pragma unroll
    for (int dt = 0; dt < 8; ++dt) o[dt] = f32x4{0.f, 0.f, 0.f, 0.f};
    float m_i[4], l_i[4];
#pragma unroll
    for (int r = 0; r < 4; ++r) { m_i[r] = NEG; l_i[r] = 0.f; }
    const int nkt = (q0 + 64) / 32;
    for (int itx = 0; itx < nkt; ++itx) {
        const int kt = itx * 32;
        if (seg[b * S + kt + 31] < seg_lo) continue;
        {
            const int kk = tid >> 3, d0 = (tid & 7) * 16;
            const float* kb = k + (((size_t)b * S + kt + kk) * H + h) * Dd + d0;
            const float* vb = v + (((size_t)b * S + kt + kk) * H + h) * Dd + d0;
#pragma unroll
            for (int j = 0; j < 4; ++j) {
                f32x4 x = *(const f32x4*)(kb + j * 4);
#pragma unroll
                for (int i = 0; i < 4; ++i) {
                    short hb = f2bs(x[i]);
                    Kh[kk][d0 + j * 4 + i] = hb;
                    Kl[kk][d0 + j * 4 + i] = f2bs(x[i] - bs2f(hb));
                }
                f32x4 y = *(const f32x4*)(vb + j * 4);
#pragma unroll
                for (int i = 0; i < 4; ++i) Vt[d0 + j * 4 + i][kk] = f2bs(y[i]);
            }
        }
        __syncthreads();
        float sc_[2][4];
#pragma unroll
        for (int nt = 0; nt < 2; ++nt) {
            f32x4 s = f32x4{0.f, 0.f, 0.f, 0.f};
#pragma unroll
            for (int c = 0; c < 4; ++c) {
                v8s kfh = *(const v8s*)&Kh[nt * 16 + l16][c * 32 + quad * 8];
                v8s kfl = *(const v8s*)&Kl[nt * 16 + l16][c * 32 + quad * 8];
                s = __builtin_amdgcn_mfma_f32_16x16x32_bf16(qh[c], kfh, s, 0, 0, 0);
                s = __builtin_amdgcn_mfma_f32_16x16x32_bf16(qlo[c], kfh, s, 0, 0, 0);
                s = __builtin_amdgcn_mfma_f32_16x16x32_bf16(qh[c], kfl, s, 0, 0, 0);
            }
            const int kj = kt + nt * 16 + l16;
            const int segk = seg[b * S + kj];
#pragma unroll
            for (int r = 0; r < 4; ++r) {
                const bool valid = (kj <= rowC0 + r) && (segk == segq[r]);
                sc_[nt][r] = valid ? s[r] : NEG;
            }
        }
        float pr[2][4];
#pragma unroll
        for (int r = 0; r < 4; ++r) {
            float mx = fmaxf(sc_[0][r], sc_[1][r]);
#pragma unroll
            for (int off = 1; off < 16; off <<= 1) mx = fmaxf(mx, __shfl_xor(mx, off));
            const float mn = fmaxf(m_i[r], mx);
            const float alpha = __expf(m_i[r] - mn);
            const float p0 = (sc_[0][r] <= 0.5f * NEG) ? 0.f : __expf(sc_[0][r] - mn);
            const float p1 = (sc_[1][r] <= 0.5f * NEG) ? 0.f : __expf(sc_[1][r] - mn);
            float rs = p0 + p1;
#pragma unroll
            for (int off = 1; off < 16; off <<= 1) rs += __shfl_xor(rs, off);
            l_i[r] = l_i[r] * alpha + rs;
            m_i[r] = mn;
#pragma unroll
            for (int dt = 0; dt < 8; ++dt) o[dt][r] *= alpha;
            pr[0][r] = p0;
            pr[1][r] = p1;
        }
#pragma unroll
        for (int nt = 0; nt < 2; ++nt)
#pragma unroll
            for (int r = 0; r < 4; ++r)
                Pl[wave][quad * 4 + r][nt * 16 + l16] = f2bs(pr[nt][r]);
        v8s pf = *(const v8s*)&Pl[wave][l16][quad * 8];
#pragma unroll
        for (int dt = 0; dt < 8; ++dt) {
            v8s vf = *(const v8s*)&Vt[dt * 16 + l16][quad * 8];
            o[dt] = __builtin_amdgcn_mfma_f32_16x16x32_bf16(pf, vf, o[dt], 0, 0, 0);
        }
        __syncthreads();
    }
    const size_t obase = (((size_t)b * S + rowC0) * H + h) * Dd;
#pragma unroll
    for (int r = 0; r < 4; ++r) {
        const float inv = 1.0f / l_i[r];
#pragma unroll
        for (int dt = 0; dt < 8; ++dt)
            out[obase + (size_t)r * H * Dd + dt * 16 + l16] = o[dt][r] * inv;
    }
}

extern "C" void kernel_launch(void* const* d_in, const int* in_sizes, int n_in,
                              void* d_out, int out_size, void* d_ws, size_t ws_size,
                              hipStream_t stream) {
    const float* q = (const float*)d_in[0];
    const float* k = (const float*)d_in[1];
    const float* v = (const float*)d_in[2];
    const int* seg = (const int*)d_in[3];
    float* out = (float*)d_out;
    const size_t need = NELEM * 2 * 3;  // Khi + Klo + Vt, bf16
    if (ws_size >= need) {
        short* khi = (short*)d_ws;
        short* klo = khi + NELEM;
        short* vtg = klo + NELEM;
        prep<<<dim3(S / 64, H, Bb), dim3(256), 0, stream>>>(k, v, khi, klo, vtg);
        fa2<<<dim3(S / BQ, H, Bb), dim3(256), 0, stream>>>(khi, klo, vtg, q, seg, out);
    } else {
        fa_slow<<<dim3(S / 64, H, Bb), dim3(256), 0, stream>>>(q, k, v, seg, out);
    }
}